// Round 6
// baseline (277.859 us; speedup 1.0000x reference)
//
#include <hip/hip_runtime.h>
#include <hip/hip_bf16.h>

#define CN 1024
#define BN 256
#define SMEM_BYTES 118016

typedef __attribute__((ext_vector_type(4))) float f32x4;
typedef __attribute__((ext_vector_type(8))) short bf16x8;

__device__ __forceinline__ short f2bf(float f) {
    __hip_bfloat16 h = __float2bfloat16(f);
    return *reinterpret_cast<short*>(&h);
}
__device__ __forceinline__ float sigm(float x) {
    return __builtin_amdgcn_rcpf(1.f + __expf(-x));
}
__device__ __forceinline__ float tanh_fast(float x) {
    return 1.f - 2.f * __builtin_amdgcn_rcpf(1.f + __expf(2.f * x));
}

// sigma k-mapping used on BOTH mfma operands (bijective on [0,64)):
//   k(q, kh, slot i) = 32*kh + 16*(i>>2) + 4*q + (i&3)
// Weights are A-side: frag(tile,kh): lane(l15,q), slot i = W[k][tile*16+l15].
// Data (h/ce/stage outputs) are B-side: lane(l15=concept,q), slot i = X[concept][k]
//   = four f32x4 loads per row at col offsets {0,16,32,48} + 4q, packed in order.

// ---------------- prep kernel ----------------
// blocks [0,14): weight repack (56 col-tiles). block 14: bias table.
// blocks [15,79): per-b tables, wave per b.
__global__ __launch_bounds__(256) void gkt_prep(
    const int* __restrict__ xt, const int* __restrict__ qt,
    const float* __restrict__ ht, const float* __restrict__ emb_x,
    const float* __restrict__ emb_c,
    const float* __restrict__ fs_W1, const float* __restrict__ fs_b1,
    const float* __restrict__ fs_W2, const float* __restrict__ fs_b2,
    const float* __restrict__ fn0_W1, const float* __restrict__ fn0_b1,
    const float* __restrict__ fn0_W2, const float* __restrict__ fn0_b2,
    const float* __restrict__ fn1_W1, const float* __restrict__ fn1_b1,
    const float* __restrict__ fn1_W2, const float* __restrict__ fn1_b2,
    const float* __restrict__ erase_W, const float* __restrict__ erase_b,
    const float* __restrict__ add_W, const float* __restrict__ add_b,
    const float* __restrict__ gru_Wih, const float* __restrict__ gru_bih,
    const float* __restrict__ gru_Whh, const float* __restrict__ gru_bhh,
    short* __restrict__ wrepack, float* __restrict__ biasc,
    float* __restrict__ perb, int* __restrict__ qtsA,
    int* __restrict__ maskA, int* __restrict__ xeA)
{
    int bid = blockIdx.x;
    int tid = threadIdx.x;
    int lane = tid & 63, wv = tid >> 6;
    int l15 = lane & 15, q = lane >> 4;
    __shared__ float inp[4][128];
    __shared__ float t1s[4][64];

    if (bid < 14) {
        int t = bid * 4 + wv;           // col-tile in [0,56)
        int colg = t * 16 + l15;
#pragma unroll
        for (int kh = 0; kh < 2; ++kh) {
            short v8[8];
#pragma unroll
            for (int i = 0; i < 8; ++i) {
                int k = kh * 32 + ((i >> 2) << 4) + (q << 2) + (i & 3);
                float v;
                if (colg < 64)       v = fn0_W1[(128 + k) * 64 + colg];
                else if (colg < 128) v = fn1_W1[(128 + k) * 64 + (colg - 64)];
                else if (colg < 320) v = gru_Whh[k * 192 + (colg - 128)];
                else if (colg < 384) v = fn0_W2[k * 64 + (colg - 320)];
                else if (colg < 448) v = fn1_W2[k * 64 + (colg - 384)];
                else if (colg < 512) v = erase_W[k * 64 + (colg - 448)];
                else if (colg < 576) v = add_W[k * 64 + (colg - 512)];
                else if (colg < 768) v = gru_Wih[k * 192 + (colg - 576)];
                else if (colg < 832) v = fn0_W1[(192 + k) * 64 + (colg - 768)];
                else                 v = fn1_W1[(192 + k) * 64 + (colg - 832)];
                v8[i] = f2bf(v);
            }
            short* dst = wrepack + ((size_t)(t * 2 + kh) * 64 + lane) * 8;
#pragma unroll
            for (int i = 0; i < 8; ++i) dst[i] = v8[i];
        }
    } else if (bid == 14) {
        // bias table (640):
        // [0,64) fn0_b1 | [64,128) fn1_b1 | [128,192) bih_r+bhh_r |
        // [192,256) bih_z+bhh_z | [256,320) bih_n | [320,384) fn0_b2 |
        // [384,448) fn1_b2 | [448,512) erase_b | [512,576) add_b | [576,640) bhh_n
        for (int g = tid; g < 640; g += 256) {
            float v;
            if (g < 64)       v = fn0_b1[g];
            else if (g < 128) v = fn1_b1[g - 64];
            else if (g < 192) v = gru_bih[g - 128] + gru_bhh[g - 128];
            else if (g < 256) v = gru_bih[g - 128] + gru_bhh[g - 128];
            else if (g < 320) v = gru_bih[128 + (g - 256)];
            else if (g < 384) v = fn0_b2[g - 320];
            else if (g < 448) v = fn1_b2[g - 384];
            else if (g < 512) v = erase_b[g - 448];
            else if (g < 576) v = add_b[g - 512];
            else              v = gru_bhh[128 + (g - 576)];
            biasc[g] = v;
        }
    } else {
        int b = (bid - 15) * 4 + wv;
        int qv = qt[b];
        int mki = (qv != -1);
        int qs = min(max(qv, 0), CN - 1);
        int xe = xt[b];
        float cq = mki ? emb_x[(size_t)xe * 64 + lane]
                       : emb_c[(size_t)CN * 64 + lane];
        inp[wv][lane]      = ht[((size_t)b * CN + qs) * 64 + lane];
        inp[wv][64 + lane] = cq;
        float p0 = 0.f, p1 = 0.f, fs = 0.f;
        for (int k = 0; k < 128; ++k) {
            float xk = inp[wv][k];
            p0 += xk * fn0_W1[k * 64 + lane];
            p1 += xk * fn1_W1[k * 64 + lane];
            fs += xk * fs_W1[k * 64 + lane];
        }
        t1s[wv][lane] = fmaxf(fs + fs_b1[lane], 0.f);
        float sf = 0.f;
        for (int k = 0; k < 64; ++k) sf += t1s[wv][k] * fs_W2[k * 64 + lane];
        sf = fmaxf(sf + fs_b2[lane], 0.f);
        float* pd = perb + (size_t)b * 192;
        pd[lane] = p0; pd[64 + lane] = p1; pd[128 + lane] = sf;
        if (lane == 0) { qtsA[b] = qs; maskA[b] = mki; xeA[b] = xe; }
    }
}

// ---------------- main fused kernel ----------------
// Operand order: A = weight frag (sigma repack), B = data frag.
#define MFMA(wa, xb, c) __builtin_amdgcn_mfma_f32_16x16x32_bf16((wa), (xb), (c), 0, 0, 0)

__global__ __launch_bounds__(1024, 1) void gkt_main(
    const float* __restrict__ ht, const float* __restrict__ graph,
    const float* __restrict__ ea_w, const float* __restrict__ pred_W,
    const float* __restrict__ pred_b,
    const short* __restrict__ wrepack, const float* __restrict__ biasc,
    const float* __restrict__ perb, const int* __restrict__ qtsA,
    const int* __restrict__ maskA, const int* __restrict__ xeA,
    const float* __restrict__ emb_x, const float* __restrict__ emb_c,
    float* __restrict__ out)
{
    extern __shared__ char smem[];
    short* FRs    = (short*)smem;                  // 114688 B: 112 frags
    float* s_bias = (float*)(smem + 114688);       // 2560 B (640 f32)
    float* s_pre  = (float*)(smem + 117248);       // 768 B: pre0|pre1|sf

    int tid = threadIdx.x;
    int lane = tid & 63, w = tid >> 6;
    int l15 = lane & 15, q = lane >> 4;
    int b = blockIdx.x;

    {
        const f32x4* src = (const f32x4*)wrepack;  // 7168 x 16B
        f32x4* dst = (f32x4*)FRs;
        for (int i = tid; i < 7168; i += 1024) dst[i] = src[i];
        if (tid < 640) s_bias[tid] = biasc[tid];
        const float* pd = perb + (size_t)b * 192;
        if (tid >= 640 && tid < 832) s_pre[tid - 640] = pd[tid - 640];
    }
    int qts = qtsA[b];
    int mk  = maskA[b];
    int xe  = xeA[b];
    __syncthreads();

    const bf16x8* FR = (const bf16x8*)FRs;
    f32x4 zero4 = {0.f, 0.f, 0.f, 0.f};
    float pb0 = pred_b[0];
    // per-lane pred_W slice: j = 16t + 4q + r
    f32x4 pw0 = *(const f32x4*)(pred_W + 4 * q);
    f32x4 pw1 = *(const f32x4*)(pred_W + 16 + 4 * q);
    f32x4 pw2 = *(const f32x4*)(pred_W + 32 + 4 * q);
    f32x4 pw3 = *(const f32x4*)(pred_W + 48 + 4 * q);

    for (int rt = 0; rt < 4; ++rt) {
        int c0 = w * 64 + rt * 16;
        int cr = c0 + l15;                       // this lane's concept
        const float* hrow = ht + ((size_t)b * CN + cr) * 64 + 4 * q;
        f32x4 v0 = *(const f32x4*)(hrow);
        f32x4 v1 = *(const f32x4*)(hrow + 16);
        f32x4 v2 = *(const f32x4*)(hrow + 32);
        f32x4 v3 = *(const f32x4*)(hrow + 48);

        if (!mk) {
            float yp = 0.f;
#pragma unroll
            for (int i = 0; i < 4; ++i)
                yp += v0[i] * pw0[i] + v1[i] * pw1[i] + v2[i] * pw2[i] + v3[i] * pw3[i];
            yp += __shfl_xor(yp, 16);
            yp += __shfl_xor(yp, 32);
            if (q == 0) out[(size_t)b * CN + cr] = yp + pb0;
            continue;
        }

        bool isq = (cr == qts);
        const float* ep = isq ? (emb_x + (size_t)xe * 64)
                              : (emb_c + (size_t)cr * 64);
        f32x4 e0 = *(const f32x4*)(ep + 4 * q);
        f32x4 e1 = *(const f32x4*)(ep + 16 + 4 * q);
        f32x4 e2 = *(const f32x4*)(ep + 32 + 4 * q);
        f32x4 e3 = *(const f32x4*)(ep + 48 + 4 * q);

        // B-operand packs (sigma order): kh0 = {tile0, tile1}, kh1 = {tile2, tile3}
        bf16x8 hB0, hB1, cB0, cB1;
#pragma unroll
        for (int i = 0; i < 4; ++i) {
            hB0[i] = f2bf(v0[i]); hB0[4 + i] = f2bf(v1[i]);
            hB1[i] = f2bf(v2[i]); hB1[4 + i] = f2bf(v3[i]);
            cB0[i] = f2bf(e0[i]); cB0[4 + i] = f2bf(e1[i]);
            cB1[i] = f2bf(e2[i]); cB1[4 + i] = f2bf(e3[i]);
        }

        // per-concept scalars (one each per lane now)
        float adjs  = graph[(size_t)qts * CN + cr];
        float radjs = graph[(size_t)cr * CN + qts];
        float eas   = ea_w[cr];

        // ---- stage 1: x = relu(h@W1h + ce@W1c + pre + b1); fn0 (t<4), fn1 (t>=4)
        bf16x8 x0B0, x0B1, x1B0, x1B1;
#pragma unroll
        for (int t = 0; t < 8; ++t) {
            f32x4 acc = MFMA(FR[(2 * t) * 64 + lane], hB0, zero4);
            acc = MFMA(FR[(2 * t + 1) * 64 + lane], hB1, acc);
            acc = MFMA(FR[(96 + 2 * t) * 64 + lane], cB0, acc);
            acc = MFMA(FR[(97 + 2 * t) * 64 + lane], cB1, acc);
            int jb = (t & 3) * 16 + 4 * q;
            f32x4 prev = *(const f32x4*)(s_pre + ((t < 4) ? 0 : 64) + jb);
            f32x4 bv   = *(const f32x4*)(s_bias + t * 16 + 4 * q);
#pragma unroll
            for (int r = 0; r < 4; ++r) {
                short us = f2bf(fmaxf(acc[r] + prev[r] + bv[r], 0.f));
                if      (t == 0) x0B0[r] = us;
                else if (t == 1) x0B0[4 + r] = us;
                else if (t == 2) x0B1[r] = us;
                else if (t == 3) x0B1[4 + r] = us;
                else if (t == 4) x1B0[r] = us;
                else if (t == 5) x1B0[4 + r] = us;
                else if (t == 6) x1B1[r] = us;
                else             x1B1[4 + r] = us;
            }
        }

        // ---- stage 2: f0/f1; m = adj*f0 + radj*f1 (self_feat at c==qts) ----
        f32x4 mreg0, mreg1, mreg2, mreg3;
        bf16x8 mB0, mB1;
#pragma unroll
        for (int t = 0; t < 4; ++t) {
            f32x4 f0a = MFMA(FR[(40 + 2 * t) * 64 + lane], x0B0, zero4);
            f0a = MFMA(FR[(41 + 2 * t) * 64 + lane], x0B1, f0a);
            f32x4 f1a = MFMA(FR[(48 + 2 * t) * 64 + lane], x1B0, zero4);
            f1a = MFMA(FR[(49 + 2 * t) * 64 + lane], x1B1, f1a);
            int jb = t * 16 + 4 * q;
            f32x4 b0v = *(const f32x4*)(s_bias + 320 + jb);
            f32x4 b1v = *(const f32x4*)(s_bias + 384 + jb);
            f32x4 sfv = *(const f32x4*)(s_pre + 128 + jb);
#pragma unroll
            for (int r = 0; r < 4; ++r) {
                float f0 = fmaxf(f0a[r] + b0v[r], 0.f);
                float f1 = fmaxf(f1a[r] + b1v[r], 0.f);
                float mv = adjs * f0 + radjs * f1;
                mv = isq ? sfv[r] : mv;
                if      (t == 0) { mreg0[r] = mv; mB0[r] = f2bf(mv); }
                else if (t == 1) { mreg1[r] = mv; mB0[4 + r] = f2bf(mv); }
                else if (t == 2) { mreg2[r] = mv; mB1[r] = f2bf(mv); }
                else             { mreg3[r] = mv; mB1[4 + r] = f2bf(mv); }
            }
        }

        // ---- stage 3: erase/add; m' = m*(1 - w*e) + w*a ----
        bf16x8 pB0, pB1;
#pragma unroll
        for (int t = 0; t < 4; ++t) {
            f32x4 eacc = MFMA(FR[(56 + 2 * t) * 64 + lane], mB0, zero4);
            eacc = MFMA(FR[(57 + 2 * t) * 64 + lane], mB1, eacc);
            f32x4 aacc = MFMA(FR[(64 + 2 * t) * 64 + lane], mB0, zero4);
            aacc = MFMA(FR[(65 + 2 * t) * 64 + lane], mB1, aacc);
            int jb = t * 16 + 4 * q;
            f32x4 bev = *(const f32x4*)(s_bias + 448 + jb);
            f32x4 bav = *(const f32x4*)(s_bias + 512 + jb);
#pragma unroll
            for (int r = 0; r < 4; ++r) {
                float eg = sigm(eacc[r] + bev[r]);
                float af = tanh_fast(aacc[r] + bav[r]);
                float mr = (t == 0) ? mreg0[r] : (t == 1) ? mreg1[r]
                         : (t == 2) ? mreg2[r] : mreg3[r];
                float mp = mr * (1.f - eas * eg) + eas * af;
                if      (t == 0) pB0[r] = f2bf(mp);
                else if (t == 1) pB0[4 + r] = f2bf(mp);
                else if (t == 2) pB1[r] = f2bf(mp);
                else             pB1[4 + r] = f2bf(mp);
            }
        }

        // ---- stage 4: GRU + prediction (per tile t to cap live regs) ----
        float yp = 0.f;
#pragma unroll
        for (int t = 0; t < 4; ++t) {
            int jb = t * 16 + 4 * q;
            // r-gate: Wih cols [0,64) frags 72+, Whh cols [0,64) frags 16+
            f32x4 gir = MFMA(FR[(72 + 2 * t) * 64 + lane], pB0, zero4);
            gir = MFMA(FR[(73 + 2 * t) * 64 + lane], pB1, gir);
            f32x4 ghr = MFMA(FR[(16 + 2 * t) * 64 + lane], hB0, zero4);
            ghr = MFMA(FR[(17 + 2 * t) * 64 + lane], hB1, ghr);
            f32x4 brv = *(const f32x4*)(s_bias + 128 + jb);
            f32x4 rg;
#pragma unroll
            for (int r = 0; r < 4; ++r) rg[r] = sigm(gir[r] + ghr[r] + brv[r]);
            // n-gate: cols [128,192): frags 88+ / 32+, split biases
            f32x4 gin = MFMA(FR[(88 + 2 * t) * 64 + lane], pB0, zero4);
            gin = MFMA(FR[(89 + 2 * t) * 64 + lane], pB1, gin);
            f32x4 ghn = MFMA(FR[(32 + 2 * t) * 64 + lane], hB0, zero4);
            ghn = MFMA(FR[(33 + 2 * t) * 64 + lane], hB1, ghn);
            f32x4 binv = *(const f32x4*)(s_bias + 256 + jb);
            f32x4 bhnv = *(const f32x4*)(s_bias + 576 + jb);
            f32x4 ng;
#pragma unroll
            for (int r = 0; r < 4; ++r)
                ng[r] = tanh_fast(gin[r] + binv[r] + rg[r] * (ghn[r] + bhnv[r]));
            // z-gate: cols [64,128): frags 80+ / 24+
            f32x4 giz = MFMA(FR[(80 + 2 * t) * 64 + lane], pB0, zero4);
            giz = MFMA(FR[(81 + 2 * t) * 64 + lane], pB1, giz);
            f32x4 ghz = MFMA(FR[(24 + 2 * t) * 64 + lane], hB0, zero4);
            ghz = MFMA(FR[(25 + 2 * t) * 64 + lane], hB1, ghz);
            f32x4 bzv = *(const f32x4*)(s_bias + 192 + jb);
            f32x4 hvv = (t == 0) ? v0 : (t == 1) ? v1 : (t == 2) ? v2 : v3;
            f32x4 pwv = (t == 0) ? pw0 : (t == 1) ? pw1 : (t == 2) ? pw2 : pw3;
#pragma unroll
            for (int r = 0; r < 4; ++r) {
                float z = sigm(giz[r] + ghz[r] + bzv[r]);
                float hn = (1.f - z) * ng[r] + z * hvv[r];
                yp += hn * pwv[r];
            }
        }
        yp += __shfl_xor(yp, 16);
        yp += __shfl_xor(yp, 32);
        if (q == 0) out[(size_t)b * CN + cr] = sigm(yp + pb0);
    }
}

extern "C" void kernel_launch(void* const* d_in, const int* in_sizes, int n_in,
                              void* d_out, int out_size, void* d_ws, size_t ws_size,
                              hipStream_t stream) {
    (void)in_sizes; (void)n_in; (void)out_size; (void)ws_size;
    const int*   xt      = (const int*)d_in[0];
    const int*   qt      = (const int*)d_in[1];
    const float* ht      = (const float*)d_in[2];
    const float* graph   = (const float*)d_in[3];
    const float* emb_x   = (const float*)d_in[4];
    const float* emb_c   = (const float*)d_in[5];
    const float* fs_W1   = (const float*)d_in[6];
    const float* fs_b1   = (const float*)d_in[7];
    const float* fs_W2   = (const float*)d_in[8];
    const float* fs_b2   = (const float*)d_in[9];
    const float* fn0_W1  = (const float*)d_in[10];
    const float* fn0_b1  = (const float*)d_in[11];
    const float* fn0_W2  = (const float*)d_in[12];
    const float* fn0_b2  = (const float*)d_in[13];
    const float* fn1_W1  = (const float*)d_in[14];
    const float* fn1_b1  = (const float*)d_in[15];
    const float* fn1_W2  = (const float*)d_in[16];
    const float* fn1_b2  = (const float*)d_in[17];
    const float* ea_w    = (const float*)d_in[18];
    const float* erase_W = (const float*)d_in[19];
    const float* erase_b = (const float*)d_in[20];
    const float* add_W   = (const float*)d_in[21];
    const float* add_b   = (const float*)d_in[22];
    const float* gru_Wih = (const float*)d_in[23];
    const float* gru_bih = (const float*)d_in[24];
    const float* gru_Whh = (const float*)d_in[25];
    const float* gru_bhh = (const float*)d_in[26];
    const float* pred_W  = (const float*)d_in[27];
    const float* pred_b  = (const float*)d_in[28];

    char* ws = (char*)d_ws;
    short* wrepack = (short*)(ws);            // 114688 B
    float* biasc   = (float*)(ws + 114688);   // 2560 B
    float* perb    = (float*)(ws + 117760);   // 196608 B
    int*   qtsA    = (int*)(ws + 314368);     // 1024 B
    int*   maskA   = (int*)(ws + 315392);     // 1024 B
    int*   xeA     = (int*)(ws + 316416);     // 1024 B

    (void)hipFuncSetAttribute((const void*)gkt_main,
                              hipFuncAttributeMaxDynamicSharedMemorySize,
                              SMEM_BYTES);

    gkt_prep<<<79, 256, 0, stream>>>(
        xt, qt, ht, emb_x, emb_c,
        fs_W1, fs_b1, fs_W2, fs_b2,
        fn0_W1, fn0_b1, fn0_W2, fn0_b2,
        fn1_W1, fn1_b1, fn1_W2, fn1_b2,
        erase_W, erase_b, add_W, add_b,
        gru_Wih, gru_bih, gru_Whh, gru_bhh,
        wrepack, biasc, perb, qtsA, maskA, xeA);

    gkt_main<<<BN, 1024, SMEM_BYTES, stream>>>(
        ht, graph, ea_w, pred_W, pred_b,
        wrepack, biasc, perb, qtsA, maskA, xeA,
        emb_x, emb_c, (float*)d_out);
}

// Round 7
// 272.525 us; speedup vs baseline: 1.0196x; 1.0196x over previous
//
#include <hip/hip_runtime.h>
#include <hip/hip_bf16.h>

#define CN 1024
#define BN 256
#define SMEM_BYTES 118016

typedef __attribute__((ext_vector_type(4))) float f32x4;
typedef __attribute__((ext_vector_type(8))) short bf16x8;

__device__ __forceinline__ short f2bf(float f) {
    __hip_bfloat16 h = __float2bfloat16(f);
    return *reinterpret_cast<short*>(&h);
}
__device__ __forceinline__ float bf2f(short u) {
    union { unsigned int i; float f; } v;
    v.i = ((unsigned int)(unsigned short)u) << 16;
    return v.f;
}
__device__ __forceinline__ float sigm(float x) {
    return __builtin_amdgcn_rcpf(1.f + __expf(-x));
}
__device__ __forceinline__ float tanh_fast(float x) {
    return 1.f - 2.f * __builtin_amdgcn_rcpf(1.f + __expf(2.f * x));
}

// sigma k-mapping used on BOTH mfma operands (bijective on [0,64)):
//   k(q, kh, slot i) = 32*kh + 16*(i>>2) + 4*q + (i&3)
// Weights are A-side: frag(tile,kh): lane(l15,q), slot i = W[k][tile*16+l15].
// Data (h/ce/stage outputs) are B-side: lane(l15=concept,q), slot i = X[concept][k]
//   = four f32x4 loads per row at col offsets {0,16,32,48} + 4q, packed in order.

// ---------------- prep kernel ----------------
// blocks [0,14): weight repack (56 col-tiles). block 14: bias table.
// blocks [15,79): per-b tables, wave per b.
__global__ __launch_bounds__(256) void gkt_prep(
    const int* __restrict__ xt, const int* __restrict__ qt,
    const float* __restrict__ ht, const float* __restrict__ emb_x,
    const float* __restrict__ emb_c,
    const float* __restrict__ fs_W1, const float* __restrict__ fs_b1,
    const float* __restrict__ fs_W2, const float* __restrict__ fs_b2,
    const float* __restrict__ fn0_W1, const float* __restrict__ fn0_b1,
    const float* __restrict__ fn0_W2, const float* __restrict__ fn0_b2,
    const float* __restrict__ fn1_W1, const float* __restrict__ fn1_b1,
    const float* __restrict__ fn1_W2, const float* __restrict__ fn1_b2,
    const float* __restrict__ erase_W, const float* __restrict__ erase_b,
    const float* __restrict__ add_W, const float* __restrict__ add_b,
    const float* __restrict__ gru_Wih, const float* __restrict__ gru_bih,
    const float* __restrict__ gru_Whh, const float* __restrict__ gru_bhh,
    short* __restrict__ wrepack, float* __restrict__ biasc,
    float* __restrict__ perb, int* __restrict__ qtsA,
    int* __restrict__ maskA, int* __restrict__ xeA)
{
    int bid = blockIdx.x;
    int tid = threadIdx.x;
    int lane = tid & 63, wv = tid >> 6;
    int l15 = lane & 15, q = lane >> 4;
    __shared__ float inp[4][128];
    __shared__ float t1s[4][64];

    if (bid < 14) {
        int t = bid * 4 + wv;           // col-tile in [0,56)
        int colg = t * 16 + l15;
#pragma unroll
        for (int kh = 0; kh < 2; ++kh) {
            short v8[8];
#pragma unroll
            for (int i = 0; i < 8; ++i) {
                int k = kh * 32 + ((i >> 2) << 4) + (q << 2) + (i & 3);
                float v;
                if (colg < 64)       v = fn0_W1[(128 + k) * 64 + colg];
                else if (colg < 128) v = fn1_W1[(128 + k) * 64 + (colg - 64)];
                else if (colg < 320) v = gru_Whh[k * 192 + (colg - 128)];
                else if (colg < 384) v = fn0_W2[k * 64 + (colg - 320)];
                else if (colg < 448) v = fn1_W2[k * 64 + (colg - 384)];
                else if (colg < 512) v = erase_W[k * 64 + (colg - 448)];
                else if (colg < 576) v = add_W[k * 64 + (colg - 512)];
                else if (colg < 768) v = gru_Wih[k * 192 + (colg - 576)];
                else if (colg < 832) v = fn0_W1[(192 + k) * 64 + (colg - 768)];
                else                 v = fn1_W1[(192 + k) * 64 + (colg - 832)];
                v8[i] = f2bf(v);
            }
            short* dst = wrepack + ((size_t)(t * 2 + kh) * 64 + lane) * 8;
#pragma unroll
            for (int i = 0; i < 8; ++i) dst[i] = v8[i];
        }
    } else if (bid == 14) {
        // bias table (640):
        // [0,64) fn0_b1 | [64,128) fn1_b1 | [128,192) bih_r+bhh_r |
        // [192,256) bih_z+bhh_z | [256,320) bih_n | [320,384) fn0_b2 |
        // [384,448) fn1_b2 | [448,512) erase_b | [512,576) add_b | [576,640) bhh_n
        for (int g = tid; g < 640; g += 256) {
            float v;
            if (g < 64)       v = fn0_b1[g];
            else if (g < 128) v = fn1_b1[g - 64];
            else if (g < 192) v = gru_bih[g - 128] + gru_bhh[g - 128];
            else if (g < 256) v = gru_bih[g - 128] + gru_bhh[g - 128];
            else if (g < 320) v = gru_bih[128 + (g - 256)];
            else if (g < 384) v = fn0_b2[g - 320];
            else if (g < 448) v = fn1_b2[g - 384];
            else if (g < 512) v = erase_b[g - 448];
            else if (g < 576) v = add_b[g - 512];
            else              v = gru_bhh[128 + (g - 576)];
            biasc[g] = v;
        }
    } else {
        int b = (bid - 15) * 4 + wv;
        int qv = qt[b];
        int mki = (qv != -1);
        int qs = min(max(qv, 0), CN - 1);
        int xe = xt[b];
        float cq = mki ? emb_x[(size_t)xe * 64 + lane]
                       : emb_c[(size_t)CN * 64 + lane];
        inp[wv][lane]      = ht[((size_t)b * CN + qs) * 64 + lane];
        inp[wv][64 + lane] = cq;
        float p0 = 0.f, p1 = 0.f, fs = 0.f;
        for (int k = 0; k < 128; ++k) {
            float xk = inp[wv][k];
            p0 += xk * fn0_W1[k * 64 + lane];
            p1 += xk * fn1_W1[k * 64 + lane];
            fs += xk * fs_W1[k * 64 + lane];
        }
        t1s[wv][lane] = fmaxf(fs + fs_b1[lane], 0.f);
        float sf = 0.f;
        for (int k = 0; k < 64; ++k) sf += t1s[wv][k] * fs_W2[k * 64 + lane];
        sf = fmaxf(sf + fs_b2[lane], 0.f);
        float* pd = perb + (size_t)b * 192;
        pd[lane] = p0; pd[64 + lane] = p1; pd[128 + lane] = sf;
        if (lane == 0) { qtsA[b] = qs; maskA[b] = mki; xeA[b] = xe; }
    }
}

// ---------------- main fused kernel ----------------
// Operand order: A = weight frag (sigma repack), B = data frag.
#define MFMA(wa, xb, c) __builtin_amdgcn_mfma_f32_16x16x32_bf16((wa), (xb), (c), 0, 0, 0)

__global__ __launch_bounds__(1024, 4) void gkt_main(
    const float* __restrict__ ht, const float* __restrict__ graph,
    const float* __restrict__ ea_w, const float* __restrict__ pred_W,
    const float* __restrict__ pred_b,
    const short* __restrict__ wrepack, const float* __restrict__ biasc,
    const float* __restrict__ perb, const int* __restrict__ qtsA,
    const int* __restrict__ maskA, const int* __restrict__ xeA,
    const float* __restrict__ emb_x, const float* __restrict__ emb_c,
    float* __restrict__ out)
{
    extern __shared__ char smem[];
    short* FRs    = (short*)smem;                  // 114688 B: 112 frags
    float* s_bias = (float*)(smem + 114688);       // 2560 B (640 f32)
    float* s_pre  = (float*)(smem + 117248);       // 768 B: pre0|pre1|sf

    int tid = threadIdx.x;
    int lane = tid & 63, w = tid >> 6;
    int l15 = lane & 15, q = lane >> 4;
    int b = blockIdx.x;

    {
        const f32x4* src = (const f32x4*)wrepack;  // 7168 x 16B
        f32x4* dst = (f32x4*)FRs;
        for (int i = tid; i < 7168; i += 1024) dst[i] = src[i];
        if (tid < 640) s_bias[tid] = biasc[tid];
        const float* pd = perb + (size_t)b * 192;
        if (tid >= 640 && tid < 832) s_pre[tid - 640] = pd[tid - 640];
    }
    int qts = qtsA[b];
    int mk  = maskA[b];
    int xe  = xeA[b];
    __syncthreads();

    const bf16x8* FR = (const bf16x8*)FRs;
    f32x4 zero4 = {0.f, 0.f, 0.f, 0.f};
    float pb0 = pred_b[0];
    // per-lane pred_W slice: j = 16t + 4q + r
    f32x4 pw0 = *(const f32x4*)(pred_W + 4 * q);
    f32x4 pw1 = *(const f32x4*)(pred_W + 16 + 4 * q);
    f32x4 pw2 = *(const f32x4*)(pred_W + 32 + 4 * q);
    f32x4 pw3 = *(const f32x4*)(pred_W + 48 + 4 * q);

    for (int rt = 0; rt < 4; ++rt) {
        int c0 = w * 64 + rt * 16;
        int cr = c0 + l15;                       // this lane's concept
        const float* hrow = ht + ((size_t)b * CN + cr) * 64 + 4 * q;
        f32x4 v0 = *(const f32x4*)(hrow);
        f32x4 v1 = *(const f32x4*)(hrow + 16);
        f32x4 v2 = *(const f32x4*)(hrow + 32);
        f32x4 v3 = *(const f32x4*)(hrow + 48);

        if (!mk) {
            float yp = 0.f;
#pragma unroll
            for (int i = 0; i < 4; ++i)
                yp += v0[i] * pw0[i] + v1[i] * pw1[i] + v2[i] * pw2[i] + v3[i] * pw3[i];
            yp += __shfl_xor(yp, 16);
            yp += __shfl_xor(yp, 32);
            if (q == 0) out[(size_t)b * CN + cr] = yp + pb0;
            continue;
        }

        bool isq = (cr == qts);
        const float* ep = isq ? (emb_x + (size_t)xe * 64)
                              : (emb_c + (size_t)cr * 64);
        f32x4 e0 = *(const f32x4*)(ep + 4 * q);
        f32x4 e1 = *(const f32x4*)(ep + 16 + 4 * q);
        f32x4 e2 = *(const f32x4*)(ep + 32 + 4 * q);
        f32x4 e3 = *(const f32x4*)(ep + 48 + 4 * q);

        // B-operand packs (sigma order): kh0 = {tile0, tile1}, kh1 = {tile2, tile3}
        bf16x8 hB0, hB1, cB0, cB1;
#pragma unroll
        for (int i = 0; i < 4; ++i) {
            hB0[i] = f2bf(v0[i]); hB0[4 + i] = f2bf(v1[i]);
            hB1[i] = f2bf(v2[i]); hB1[4 + i] = f2bf(v3[i]);
            cB0[i] = f2bf(e0[i]); cB0[4 + i] = f2bf(e1[i]);
            cB1[i] = f2bf(e2[i]); cB1[4 + i] = f2bf(e3[i]);
        }

        // per-concept scalars (one each per lane)
        float adjs  = graph[(size_t)qts * CN + cr];
        float radjs = graph[(size_t)cr * CN + qts];
        float eas   = ea_w[cr];

        // ---- stage 1: x = relu(h@W1h + ce@W1c + pre + b1); fn0 (t<4), fn1 (t>=4)
        bf16x8 x0B0, x0B1, x1B0, x1B1;
#pragma unroll
        for (int t = 0; t < 8; ++t) {
            f32x4 acc = MFMA(FR[(2 * t) * 64 + lane], hB0, zero4);
            acc = MFMA(FR[(2 * t + 1) * 64 + lane], hB1, acc);
            acc = MFMA(FR[(96 + 2 * t) * 64 + lane], cB0, acc);
            acc = MFMA(FR[(97 + 2 * t) * 64 + lane], cB1, acc);
            int jb = (t & 3) * 16 + 4 * q;
            f32x4 prev = *(const f32x4*)(s_pre + ((t < 4) ? 0 : 64) + jb);
            f32x4 bv   = *(const f32x4*)(s_bias + t * 16 + 4 * q);
#pragma unroll
            for (int r = 0; r < 4; ++r) {
                short us = f2bf(fmaxf(acc[r] + prev[r] + bv[r], 0.f));
                if      (t == 0) x0B0[r] = us;
                else if (t == 1) x0B0[4 + r] = us;
                else if (t == 2) x0B1[r] = us;
                else if (t == 3) x0B1[4 + r] = us;
                else if (t == 4) x1B0[r] = us;
                else if (t == 5) x1B0[4 + r] = us;
                else if (t == 6) x1B1[r] = us;
                else             x1B1[4 + r] = us;
            }
        }

        // ---- stage 2: f0/f1; m = adj*f0 + radj*f1 (self_feat at c==qts) ----
        // m kept ONLY as bf16 (mB); stage 3 re-extracts f32 via shift (negligible err)
        bf16x8 mB0, mB1;
#pragma unroll
        for (int t = 0; t < 4; ++t) {
            f32x4 f0a = MFMA(FR[(40 + 2 * t) * 64 + lane], x0B0, zero4);
            f0a = MFMA(FR[(41 + 2 * t) * 64 + lane], x0B1, f0a);
            f32x4 f1a = MFMA(FR[(48 + 2 * t) * 64 + lane], x1B0, zero4);
            f1a = MFMA(FR[(49 + 2 * t) * 64 + lane], x1B1, f1a);
            int jb = t * 16 + 4 * q;
            f32x4 b0v = *(const f32x4*)(s_bias + 320 + jb);
            f32x4 b1v = *(const f32x4*)(s_bias + 384 + jb);
            f32x4 sfv = *(const f32x4*)(s_pre + 128 + jb);
#pragma unroll
            for (int r = 0; r < 4; ++r) {
                float f0 = fmaxf(f0a[r] + b0v[r], 0.f);
                float f1 = fmaxf(f1a[r] + b1v[r], 0.f);
                float mv = adjs * f0 + radjs * f1;
                mv = isq ? sfv[r] : mv;
                short ms = f2bf(mv);
                if      (t == 0) mB0[r] = ms;
                else if (t == 1) mB0[4 + r] = ms;
                else if (t == 2) mB1[r] = ms;
                else             mB1[4 + r] = ms;
            }
        }

        // ---- stage 3: erase/add; m' = m*(1 - w*e) + w*a ----
        bf16x8 pB0, pB1;
#pragma unroll
        for (int t = 0; t < 4; ++t) {
            f32x4 eacc = MFMA(FR[(56 + 2 * t) * 64 + lane], mB0, zero4);
            eacc = MFMA(FR[(57 + 2 * t) * 64 + lane], mB1, eacc);
            f32x4 aacc = MFMA(FR[(64 + 2 * t) * 64 + lane], mB0, zero4);
            aacc = MFMA(FR[(65 + 2 * t) * 64 + lane], mB1, aacc);
            int jb = t * 16 + 4 * q;
            f32x4 bev = *(const f32x4*)(s_bias + 448 + jb);
            f32x4 bav = *(const f32x4*)(s_bias + 512 + jb);
#pragma unroll
            for (int r = 0; r < 4; ++r) {
                float eg = sigm(eacc[r] + bev[r]);
                float af = tanh_fast(aacc[r] + bav[r]);
                short mr16 = (t == 0) ? mB0[r] : (t == 1) ? mB0[4 + r]
                           : (t == 2) ? mB1[r] : mB1[4 + r];
                float mr = bf2f(mr16);
                float mp = mr * (1.f - eas * eg) + eas * af;
                if      (t == 0) pB0[r] = f2bf(mp);
                else if (t == 1) pB0[4 + r] = f2bf(mp);
                else if (t == 2) pB1[r] = f2bf(mp);
                else             pB1[4 + r] = f2bf(mp);
            }
        }

        // ---- stage 4: GRU + prediction (per tile t to cap live regs) ----
        float yp = 0.f;
#pragma unroll
        for (int t = 0; t < 4; ++t) {
            int jb = t * 16 + 4 * q;
            // r-gate: Wih cols [0,64) frags 72+, Whh cols [0,64) frags 16+
            f32x4 gir = MFMA(FR[(72 + 2 * t) * 64 + lane], pB0, zero4);
            gir = MFMA(FR[(73 + 2 * t) * 64 + lane], pB1, gir);
            f32x4 ghr = MFMA(FR[(16 + 2 * t) * 64 + lane], hB0, zero4);
            ghr = MFMA(FR[(17 + 2 * t) * 64 + lane], hB1, ghr);
            f32x4 brv = *(const f32x4*)(s_bias + 128 + jb);
            f32x4 rg;
#pragma unroll
            for (int r = 0; r < 4; ++r) rg[r] = sigm(gir[r] + ghr[r] + brv[r]);
            // n-gate: cols [128,192): frags 88+ / 32+, split biases
            f32x4 gin = MFMA(FR[(88 + 2 * t) * 64 + lane], pB0, zero4);
            gin = MFMA(FR[(89 + 2 * t) * 64 + lane], pB1, gin);
            f32x4 ghn = MFMA(FR[(32 + 2 * t) * 64 + lane], hB0, zero4);
            ghn = MFMA(FR[(33 + 2 * t) * 64 + lane], hB1, ghn);
            f32x4 binv = *(const f32x4*)(s_bias + 256 + jb);
            f32x4 bhnv = *(const f32x4*)(s_bias + 576 + jb);
            f32x4 ng;
#pragma unroll
            for (int r = 0; r < 4; ++r)
                ng[r] = tanh_fast(gin[r] + binv[r] + rg[r] * (ghn[r] + bhnv[r]));
            // z-gate: cols [64,128): frags 80+ / 24+
            f32x4 giz = MFMA(FR[(80 + 2 * t) * 64 + lane], pB0, zero4);
            giz = MFMA(FR[(81 + 2 * t) * 64 + lane], pB1, giz);
            f32x4 ghz = MFMA(FR[(24 + 2 * t) * 64 + lane], hB0, zero4);
            ghz = MFMA(FR[(25 + 2 * t) * 64 + lane], hB1, ghz);
            f32x4 bzv = *(const f32x4*)(s_bias + 192 + jb);
            f32x4 hvv = (t == 0) ? v0 : (t == 1) ? v1 : (t == 2) ? v2 : v3;
            f32x4 pwv = (t == 0) ? pw0 : (t == 1) ? pw1 : (t == 2) ? pw2 : pw3;
#pragma unroll
            for (int r = 0; r < 4; ++r) {
                float z = sigm(giz[r] + ghz[r] + bzv[r]);
                float hn = (1.f - z) * ng[r] + z * hvv[r];
                yp += hn * pwv[r];
            }
        }
        yp += __shfl_xor(yp, 16);
        yp += __shfl_xor(yp, 32);
        if (q == 0) out[(size_t)b * CN + cr] = sigm(yp + pb0);
    }
}

extern "C" void kernel_launch(void* const* d_in, const int* in_sizes, int n_in,
                              void* d_out, int out_size, void* d_ws, size_t ws_size,
                              hipStream_t stream) {
    (void)in_sizes; (void)n_in; (void)out_size; (void)ws_size;
    const int*   xt      = (const int*)d_in[0];
    const int*   qt      = (const int*)d_in[1];
    const float* ht      = (const float*)d_in[2];
    const float* graph   = (const float*)d_in[3];
    const float* emb_x   = (const float*)d_in[4];
    const float* emb_c   = (const float*)d_in[5];
    const float* fs_W1   = (const float*)d_in[6];
    const float* fs_b1   = (const float*)d_in[7];
    const float* fs_W2   = (const float*)d_in[8];
    const float* fs_b2   = (const float*)d_in[9];
    const float* fn0_W1  = (const float*)d_in[10];
    const float* fn0_b1  = (const float*)d_in[11];
    const float* fn0_W2  = (const float*)d_in[12];
    const float* fn0_b2  = (const float*)d_in[13];
    const float* fn1_W1  = (const float*)d_in[14];
    const float* fn1_b1  = (const float*)d_in[15];
    const float* fn1_W2  = (const float*)d_in[16];
    const float* fn1_b2  = (const float*)d_in[17];
    const float* ea_w    = (const float*)d_in[18];
    const float* erase_W = (const float*)d_in[19];
    const float* erase_b = (const float*)d_in[20];
    const float* add_W   = (const float*)d_in[21];
    const float* add_b   = (const float*)d_in[22];
    const float* gru_Wih = (const float*)d_in[23];
    const float* gru_bih = (const float*)d_in[24];
    const float* gru_Whh = (const float*)d_in[25];
    const float* gru_bhh = (const float*)d_in[26];
    const float* pred_W  = (const float*)d_in[27];
    const float* pred_b  = (const float*)d_in[28];

    char* ws = (char*)d_ws;
    short* wrepack = (short*)(ws);            // 114688 B
    float* biasc   = (float*)(ws + 114688);   // 2560 B
    float* perb    = (float*)(ws + 117760);   // 196608 B
    int*   qtsA    = (int*)(ws + 314368);     // 1024 B
    int*   maskA   = (int*)(ws + 315392);     // 1024 B
    int*   xeA     = (int*)(ws + 316416);     // 1024 B

    (void)hipFuncSetAttribute((const void*)gkt_main,
                              hipFuncAttributeMaxDynamicSharedMemorySize,
                              SMEM_BYTES);

    gkt_prep<<<79, 256, 0, stream>>>(
        xt, qt, ht, emb_x, emb_c,
        fs_W1, fs_b1, fs_W2, fs_b2,
        fn0_W1, fn0_b1, fn0_W2, fn0_b2,
        fn1_W1, fn1_b1, fn1_W2, fn1_b2,
        erase_W, erase_b, add_W, add_b,
        gru_Wih, gru_bih, gru_Whh, gru_bhh,
        wrepack, biasc, perb, qtsA, maskA, xeA);

    gkt_main<<<BN, 1024, SMEM_BYTES, stream>>>(
        ht, graph, ea_w, pred_W, pred_b,
        wrepack, biasc, perb, qtsA, maskA, xeA,
        emb_x, emb_c, (float*)d_out);
}